// Round 8
// baseline (2427.296 us; speedup 1.0000x reference)
//
#include <hip/hip_runtime.h>
#include <math.h>

// DGNRNetwork persistent mega-kernel: encoder -> TConv1 -> mask -> TConv2 -> head.
// N=50000, E=800000, B=1000, HID=32, HEADS=4, D1=128, FINAL=288
// fp16 downstream of encoder; qkv via MFMA 16x16x32_f16; attn = max-free softmax, two-phase.
// ONE kernel, 1536 blocks @ __launch_bounds__(256,6) (LDS 15.9KB, VGPR<=85 -> 6 blk/CU co-resident).
// Grid barrier: arrival = ONE agent-scope atomic add; spin = agent-scope atomic LOAD + s_sleep
// (R7 lesson: spinning on atomicAdd(bar,0) serializes RMWs -> ~220us/barrier; load-spin is ~us).
// CSR replaced by padded neighbor table: col[dst*128 + slot], slot from fused hist+scatter.
// Stages: S0 wt|hist+scatter|enc -> S1 qkv1 -> S2 attn1 -> S3 qkv2 -> S4 attn2 -> S5 head

typedef _Float16 half8 __attribute__((ext_vector_type(8)));
typedef _Float16 half2t __attribute__((ext_vector_type(2)));
typedef float f32x4 __attribute__((ext_vector_type(4)));

#define NBLK 1536
#define CAP 128   // padded neighbor-row capacity; Poisson(16) => P(deg>=128) ~ 0

__device__ inline half8 h8zero() {
    half8 r;
#pragma unroll
    for (int j = 0; j < 8; ++j) r[j] = (_Float16)0.f;
    return r;
}

__device__ __forceinline__ float dot8(half8 a, half8 b, float c) {
#if __has_builtin(__builtin_amdgcn_fdot2)
#pragma unroll
    for (int j = 0; j < 4; ++j) {
        half2t x, y;
        x[0] = a[2 * j]; x[1] = a[2 * j + 1];
        y[0] = b[2 * j]; y[1] = b[2 * j + 1];
        c = __builtin_amdgcn_fdot2(x, y, c, false);
    }
#else
#pragma unroll
    for (int j = 0; j < 8; ++j) c += (float)a[j] * (float)b[j];
#endif
    return c;
}

// ---- grid barrier: RMW once to arrive, then LOAD-spin (no RMW storm) ----
__device__ __forceinline__ void gsync(int* bar, int target) {
    __syncthreads();
    if (threadIdx.x == 0) {
        __threadfence();   // release our global writes to device scope
        __hip_atomic_fetch_add(bar, 1, __ATOMIC_RELEASE, __HIP_MEMORY_SCOPE_AGENT);
        while (__hip_atomic_load(bar, __ATOMIC_ACQUIRE, __HIP_MEMORY_SCOPE_AGENT) < target)
            __builtin_amdgcn_s_sleep(8);
    }
    __syncthreads();
    __threadfence();       // acquire: discard stale cached lines
}

// ---------------- encoder body: h0 = relu(relu(x@W1+b1)@W2+b2), fp16 out ----------------
__device__ __forceinline__ void enc_body(const float* __restrict__ x,
                                         const float* __restrict__ w1, const float* __restrict__ b1,
                                         const float* __restrict__ w2, const float* __restrict__ b2,
                                         _Float16* __restrict__ h0, int n, int bn,
                                         float* __restrict__ smem) {
    float* W1s = smem;          // 2048
    float* W2s = smem + 2048;   // 1024
    float* B1s = smem + 3072;   // 32
    float* B2s = smem + 3104;   // 32
    float* xs  = smem + 3136;   // 512
    float* hs  = smem + 3648;   // 256
    int t = threadIdx.x;
    for (int i = t; i < 64 * 32; i += 256) W1s[i] = w1[i];
    for (int i = t; i < 32 * 32; i += 256) W2s[i] = w2[i];
    if (t < 32) { B1s[t] = b1[t]; B2s[t] = b2[t]; }
    if (t < 128) {
        int row = t >> 4;
        float4 val = make_float4(0.f, 0.f, 0.f, 0.f);
        if (bn + row < n) val = *(const float4*)(x + (size_t)bn * 64 + t * 4);
        ((float4*)xs)[t] = val;
    }
    __syncthreads();
    int nn = t >> 5, c = t & 31;
    float acc = B1s[c];
#pragma unroll
    for (int i = 0; i < 64; ++i) acc += xs[nn * 64 + i] * W1s[i * 32 + c];
    acc = fmaxf(acc, 0.f);
    hs[nn * 32 + c] = acc;
    __syncthreads();
    float acc2 = B2s[c];
#pragma unroll
    for (int i = 0; i < 32; ++i) acc2 += hs[nn * 32 + i] * W2s[i * 32 + c];
    acc2 = fmaxf(acc2, 0.f);
    int node = bn + nn;
    if (node < n) h0[(size_t)node * 32 + c] = (_Float16)acc2;
    __syncthreads();   // smem reused by next grid-stride iteration / next stage
}

// ---------------- qkv GEMM body via MFMA (BM=64, K-tile=32, 4 waves 2x2) ----------------
__device__ __forceinline__ void qkv_body(const _Float16* __restrict__ X, const float* __restrict__ mask,
                                         const _Float16* __restrict__ WT,
                                         const float* __restrict__ Bq, const float* __restrict__ Bk,
                                         const float* __restrict__ Bv,
                                         _Float16* __restrict__ Q, _Float16* __restrict__ KV,
                                         int n, int IN, int bx, int z,
                                         _Float16* __restrict__ Xs, _Float16* __restrict__ Ws) {
    int t = threadIdx.x;
    int bm = bx * 64;
    const float* Bz = (z == 0) ? Bq : ((z == 1) ? Bk : Bv);
    _Float16* Y;
    size_t ystride;
    if (z == 0) { Y = Q; ystride = 128; }
    else        { Y = KV + (z == 1 ? 0 : 128); ystride = 256; }

    int lane = t & 63, w = t >> 6;
    int wr = w >> 1, wc = w & 1;
    int fr = lane & 15, k0 = (lane >> 4) * 8;
    f32x4 acc[2][4];
#pragma unroll
    for (int i = 0; i < 2; ++i)
#pragma unroll
        for (int j = 0; j < 4; ++j)
#pragma unroll
            for (int r = 0; r < 4; ++r) acc[i][j][r] = 0.f;

    int srow = t >> 2, sseg = (t & 3) * 8;
    int snode = bm + srow;
    const _Float16* xbase = X + (size_t)snode * IN + sseg;
    const _Float16* wbase = WT + (size_t)(z * 128) * IN + sseg;
    bool xvalid = (snode < n);
    if (xvalid && mask) xvalid = (mask[snode] != 0.f);   // mask is exactly 0/1

    for (int kt = 0; kt < IN; kt += 32) {
        half8 xv = h8zero();
        if (xvalid) xv = *(const half8*)(xbase + kt);
        half8 wv0 = *(const half8*)(wbase + (size_t)srow * IN + kt);
        half8 wv1 = *(const half8*)(wbase + (size_t)(64 + srow) * IN + kt);
        __syncthreads();
        *(half8*)&Xs[srow * 40 + sseg] = xv;
        *(half8*)&Ws[srow * 40 + sseg] = wv0;
        *(half8*)&Ws[(64 + srow) * 40 + sseg] = wv1;
        __syncthreads();
        half8 a0 = *(const half8*)&Xs[(wr * 32 + fr) * 40 + k0];
        half8 a1 = *(const half8*)&Xs[(wr * 32 + 16 + fr) * 40 + k0];
#pragma unroll
        for (int tc = 0; tc < 4; ++tc) {
            half8 bfr = *(const half8*)&Ws[(wc * 64 + tc * 16 + fr) * 40 + k0];
            acc[0][tc] = __builtin_amdgcn_mfma_f32_16x16x32_f16(a0, bfr, acc[0][tc], 0, 0, 0);
            acc[1][tc] = __builtin_amdgcn_mfma_f32_16x16x32_f16(a1, bfr, acc[1][tc], 0, 0, 0);
        }
    }
#pragma unroll
    for (int tc = 0; tc < 4; ++tc) {
        int colc = wc * 64 + tc * 16 + fr;
        float bias = Bz[colc];
#pragma unroll
        for (int tr = 0; tr < 2; ++tr) {
#pragma unroll
            for (int reg = 0; reg < 4; ++reg) {
                int node = bm + wr * 32 + tr * 16 + (lane >> 4) * 4 + reg;
                if (node < n) Y[(size_t)node * ystride + colc] = (_Float16)(acc[tr][tc][reg] + bias);
            }
        }
    }
    __syncthreads();   // smem reused next iteration
}

// ---------------- attention body: one wave per node, two-phase, max-free softmax ----------
__device__ __forceinline__ void attn_body(const _Float16* __restrict__ q,
                                          const _Float16* __restrict__ kv,
                                          const int* __restrict__ deg, const int* __restrict__ col,
                                          _Float16* __restrict__ out, int n, int node) {
    int lane = threadIdx.x & 63;
    if (node >= n) return;   // no syncthreads below
    int eo  = lane >> 2;
    int hq  = lane & 3;
    int dl  = lane & 15;
    int sub = lane >> 4;
    int hd  = dl >> 2;

    const _Float16* qp = q + (size_t)node * 128 + hq * 32;
    half8 q0 = *(const half8*)(qp);
    half8 q1 = *(const half8*)(qp + 8);
    half8 q2 = *(const half8*)(qp + 16);
    half8 q3 = *(const half8*)(qp + 24);

    int start = node * CAP;
    int len = deg[node];
    len = (len > CAP) ? CAP : len;
    float s = 0.f;
    float acc[8];
#pragma unroll
    for (int j = 0; j < 8; ++j) acc[j] = 0.f;
    const float sc = 0.17677669529663689f * 1.4426950408889634f;  // 1/sqrt(32) * log2(e)

    for (int base = 0; base < len; base += 16) {
        int rem = len - base;
        int i = base + eo;
        bool valid = (i < len);
        int srcn = valid ? col[start + i] : 0;
        const _Float16* kp = kv + (size_t)srcn * 256 + hq * 32;
        half8 k0 = *(const half8*)(kp);
        half8 k1 = *(const half8*)(kp + 8);
        half8 k2 = *(const half8*)(kp + 16);
        half8 k3 = *(const half8*)(kp + 24);
        float dot = 0.f;
        dot = dot8(q0, k0, dot);
        dot = dot8(q1, k1, dot);
        dot = dot8(q2, k2, dot);
        dot = dot8(q3, k3, dot);
        float a = fminf(fmaxf(dot * sc, -120.f), 120.f);
        float p = valid ? __builtin_amdgcn_exp2f(a) : 0.f;
        int ng = (rem >= 16) ? 4 : ((rem + 3) >> 2);
        for (int g = 0; g < ng; ++g) {
            int e = g * 4 + sub;
            float pj = __shfl(p, e * 4 + hd);
            int   sj = __shfl(srcn, e * 4);
            half8 vf = *(const half8*)(kv + (size_t)sj * 256 + 128 + dl * 8);
            s += pj;
#pragma unroll
            for (int j = 0; j < 8; ++j) acc[j] += pj * (float)vf[j];
        }
    }
#pragma unroll
    for (int mask = 16; mask <= 32; mask <<= 1) {
        s += __shfl_xor(s, mask);
#pragma unroll
        for (int j = 0; j < 8; ++j) acc[j] += __shfl_xor(acc[j], mask);
    }
    if (sub == 0) {
        float inv = 1.f / (s + 1e-16f);
        half8 r;
#pragma unroll
        for (int j = 0; j < 8; ++j) r[j] = (_Float16)fmaxf(acc[j] * inv, 0.f);
        *(half8*)(out + (size_t)node * 128 + dl * 8) = r;
    }
}

// ---------------- THE mega-kernel ----------------
__global__ __launch_bounds__(256, 6)
void mega_kernel(const float* __restrict__ x, const int* __restrict__ srcv,
                 const int* __restrict__ dstv, const float* __restrict__ dm,
                 const int* __restrict__ gi,
                 const float* __restrict__ ew1, const float* __restrict__ eb1,
                 const float* __restrict__ ew2, const float* __restrict__ eb2,
                 const float* __restrict__ q1w, const float* __restrict__ q1b,
                 const float* __restrict__ k1w, const float* __restrict__ k1b,
                 const float* __restrict__ v1w, const float* __restrict__ v1b,
                 const float* __restrict__ q2w, const float* __restrict__ q2b,
                 const float* __restrict__ k2w, const float* __restrict__ k2b,
                 const float* __restrict__ v2w, const float* __restrict__ v2b,
                 const float* __restrict__ ow, const float* __restrict__ ob,
                 float* __restrict__ out,
                 _Float16* __restrict__ h0, _Float16* __restrict__ h1, _Float16* __restrict__ h2,
                 _Float16* __restrict__ Q, _Float16* __restrict__ KV,
                 _Float16* __restrict__ WT1, _Float16* __restrict__ WT2,
                 int* __restrict__ bar, int* __restrict__ deg, int* __restrict__ colb,
                 int n, int e, int bsz,
                 int wtb, int eb, int encb, int nqx, int nattn) {
    __shared__ float smem[3904];                 // 15616 B; reused by enc (f32) and qkv (f16)
    _Float16* Xs = (_Float16*)smem;              // 64*40 halfs
    _Float16* Wsh = Xs + 64 * 40;                // 128*40 halfs
    int t = threadIdx.x;

    // ---- S0: wt | hist+scatter | enc ----
    int s0 = wtb + eb + encb;
    for (int b = blockIdx.x; b < s0; b += NBLK) {
        if (b < wtb) {
            int tid = b * 256 + t;
            const int n1 = 3 * 128 * 32;
            if (tid < n1) {
                int z = tid / (128 * 32);
                int rem = tid % (128 * 32);
                int c = rem / 32, k = rem % 32;
                const float* wsrc = (z == 0) ? q1w : ((z == 1) ? k1w : v1w);
                WT1[tid] = (_Float16)wsrc[k * 128 + c];
            } else {
                int i = tid - n1;
                if (i < 3 * 128 * 128) {
                    int z = i / (128 * 128);
                    int rem = i % (128 * 128);
                    int c = rem / 128, k = rem % 128;
                    const float* wsrc = (z == 0) ? q2w : ((z == 1) ? k2w : v2w);
                    WT2[i] = (_Float16)wsrc[k * 128 + c];
                }
            }
        } else if (b < wtb + eb) {
            int i = (b - wtb) * 256 + t;
            if (i < e) {
                int d = dstv[i];
                int slot = atomicAdd(&deg[d], 1);
                if (slot < CAP) colb[d * CAP + slot] = srcv[i];
            }
        } else {
            enc_body(x, ew1, eb1, ew2, eb2, h0, n, (b - wtb - eb) * 8, smem);
        }
    }
    gsync(bar, NBLK);

    // ---- S1: qkv1 ----
    for (int b = blockIdx.x; b < 3 * nqx; b += NBLK)
        qkv_body(h0, nullptr, WT1, q1b, k1b, v1b, Q, KV, n, 32, b % nqx, b / nqx, Xs, Wsh);
    gsync(bar, 2 * NBLK);

    // ---- S2: attn1 -> h1 ----
    for (int b = blockIdx.x; b < nattn; b += NBLK)
        attn_body(Q, KV, deg, colb, h1, n, b * 4 + (t >> 6));
    gsync(bar, 3 * NBLK);

    // ---- S3: qkv2 (input h1 * dm) ----
    for (int b = blockIdx.x; b < 3 * nqx; b += NBLK)
        qkv_body(h1, dm, WT2, q2b, k2b, v2b, Q, KV, n, 128, b % nqx, b / nqx, Xs, Wsh);
    gsync(bar, 4 * NBLK);

    // ---- S4: attn2 -> h2 ----
    for (int b = blockIdx.x; b < nattn; b += NBLK)
        attn_body(Q, KV, deg, colb, h2, n, b * 4 + (t >> 6));
    gsync(bar, 5 * NBLK);

    // ---- S5: head ----
    int hb = (bsz * 5 + 255) / 256;
    for (int b = blockIdx.x; b < hb; b += NBLK) {
        int idx = b * 256 + t;
        if (idx < bsz * 5) {
            int bb = idx / 5, c = idx % 5;
            int g = gi[bb];
            float acc = ob[c];
            const _Float16* r0 = h0 + (size_t)g * 32;
#pragma unroll
            for (int i = 0; i < 32; ++i) acc += (float)r0[i] * ow[i * 5 + c];
            const _Float16* r1 = h1 + (size_t)g * 128;
#pragma unroll
            for (int i = 0; i < 128; ++i) acc += (float)r1[i] * ow[(32 + i) * 5 + c];
            const _Float16* r2 = h2 + (size_t)g * 128;
#pragma unroll
            for (int i = 0; i < 128; ++i) acc += (float)r2[i] * ow[(160 + i) * 5 + c];
            out[idx] = acc;
        }
    }
}

extern "C" void kernel_launch(void* const* d_in, const int* in_sizes, int n_in,
                              void* d_out, int out_size, void* d_ws, size_t ws_size,
                              hipStream_t stream) {
    const float* x    = (const float*)d_in[0];
    const int*   ei   = (const int*)d_in[1];
    const float* dm   = (const float*)d_in[2];
    const int*   gi   = (const int*)d_in[3];
    const float* ew1  = (const float*)d_in[4];
    const float* eb1  = (const float*)d_in[5];
    const float* ew2  = (const float*)d_in[6];
    const float* eb2  = (const float*)d_in[7];
    const float* c1wq = (const float*)d_in[8];
    const float* c1bq = (const float*)d_in[9];
    const float* c1wk = (const float*)d_in[10];
    const float* c1bk = (const float*)d_in[11];
    const float* c1wv = (const float*)d_in[12];
    const float* c1bv = (const float*)d_in[13];
    const float* c2wq = (const float*)d_in[14];
    const float* c2bq = (const float*)d_in[15];
    const float* c2wk = (const float*)d_in[16];
    const float* c2bk = (const float*)d_in[17];
    const float* c2wv = (const float*)d_in[18];
    const float* c2bv = (const float*)d_in[19];
    const float* ow   = (const float*)d_in[20];
    const float* ob   = (const float*)d_in[21];
    float* out = (float*)d_out;

    int N = in_sizes[0] / 64;
    int E = in_sizes[1] / 2;
    int B = in_sizes[3];
    const int* srcv = ei;
    const int* dstv = ei + E;

    // workspace carve-up
    char* ws = (char*)d_ws;
    size_t off = 0;
    auto alloc = [&](size_t bytes) -> void* {
        void* p = ws + off;
        off += (bytes + 255) & ~(size_t)255;
        return p;
    };
    _Float16* h0   = (_Float16*)alloc((size_t)N * 32 * 2);
    _Float16* h1   = (_Float16*)alloc((size_t)N * 128 * 2);
    _Float16* h2   = (_Float16*)alloc((size_t)N * 128 * 2);
    _Float16* Q    = (_Float16*)alloc((size_t)N * 128 * 2);
    _Float16* KV   = (_Float16*)alloc((size_t)N * 256 * 2);
    _Float16* WT1  = (_Float16*)alloc((size_t)3 * 128 * 32 * 2);
    _Float16* WT2  = (_Float16*)alloc((size_t)3 * 128 * 128 * 2);
    int* bar   = (int*)alloc(256);                         // barrier counter (zeroed each launch)
    int* deg   = (int*)alloc((size_t)N * 4);               // contiguous with bar -> one memset
    int* colb  = (int*)alloc((size_t)N * CAP * 4);

    hipMemsetAsync(bar, 0, 256 + (size_t)N * 4, stream);   // zeroes bar AND deg (graph node)

    int eb    = (E + 255) / 256;        // 3125
    int encb  = (N + 7) / 8;            // 6250
    int nqx   = (N + 63) / 64;          // 782
    int nattn = (N + 3) / 4;            // 12500
    int wtb   = (3 * 128 * 32 + 3 * 128 * 128 + 255) / 256;   // 240

    mega_kernel<<<NBLK, 256, 0, stream>>>(
        x, srcv, dstv, dm, gi, ew1, eb1, ew2, eb2,
        c1wq, c1bq, c1wk, c1bk, c1wv, c1bv,
        c2wq, c2bq, c2wk, c2bk, c2wv, c2bv,
        ow, ob, out,
        h0, h1, h2, Q, KV, WT1, WT2,
        bar, deg, colb,
        N, E, B, wtb, eb, encb, nqx, nattn);
}

// Round 9
// 246.382 us; speedup vs baseline: 9.8518x; 9.8518x over previous
//
#include <hip/hip_runtime.h>
#include <math.h>

// DGNRNetwork: encoder MLP -> TransformerConv(32->4x32) -> mask -> TransformerConv(128->4x32) -> head
// N=50000, E=800000, B=1000, HID=32, HEADS=4, D1=128, FINAL=288
// fp16 downstream of encoder; qkv via MFMA 16x16x32_f16; attn = max-free softmax over padded
// neighbor table gathers of interleaved KV rows (256 halfs: K[0..127] | V[128..255]).
// R8 lesson: persistent mega-kernel + grid barriers = device-scope L2 flush storms on 8 XCDs.
// Multi-kernel it is. Launch graph (7 nodes):
//   memset(deg) -> prep[wt|hist+scatter|enc] -> qkv1 -> attn1 -> qkv2 -> attn2 -> head

typedef _Float16 half8 __attribute__((ext_vector_type(8)));
typedef float f32x4 __attribute__((ext_vector_type(4)));

#define CAP 128   // padded neighbor-row capacity; Poisson(16) => P(deg>CAP) ~ 1e-60, clamp guards

__device__ inline half8 h8zero() {
    half8 r;
#pragma unroll
    for (int j = 0; j < 8; ++j) r[j] = (_Float16)0.f;
    return r;
}

// ---------------- encoder body: h0 = relu(relu(x@W1+b1)@W2+b2), fp16 out ----------------
__device__ __forceinline__ void enc_body(const float* __restrict__ x,
                                         const float* __restrict__ w1, const float* __restrict__ b1,
                                         const float* __restrict__ w2, const float* __restrict__ b2,
                                         _Float16* __restrict__ h0, int n, int bn,
                                         float* __restrict__ smem) {
    float* W1s = smem;          // 2048
    float* W2s = smem + 2048;   // 1024
    float* B1s = smem + 3072;   // 32
    float* B2s = smem + 3104;   // 32
    float* xs  = smem + 3136;   // 512
    float* hs  = smem + 3648;   // 256
    int t = threadIdx.x;
    for (int i = t; i < 64 * 32; i += 256) W1s[i] = w1[i];
    for (int i = t; i < 32 * 32; i += 256) W2s[i] = w2[i];
    if (t < 32) { B1s[t] = b1[t]; B2s[t] = b2[t]; }
    if (t < 128) {  // 8 rows x 64 floats = 128 float4, contiguous
        int row = t >> 4;
        float4 val = make_float4(0.f, 0.f, 0.f, 0.f);
        if (bn + row < n) val = *(const float4*)(x + (size_t)bn * 64 + t * 4);
        ((float4*)xs)[t] = val;
    }
    __syncthreads();
    int nn = t >> 5, c = t & 31;
    float acc = B1s[c];
#pragma unroll
    for (int i = 0; i < 64; ++i) acc += xs[nn * 64 + i] * W1s[i * 32 + c];
    acc = fmaxf(acc, 0.f);
    hs[nn * 32 + c] = acc;
    __syncthreads();
    float acc2 = B2s[c];
#pragma unroll
    for (int i = 0; i < 32; ++i) acc2 += hs[nn * 32 + i] * W2s[i * 32 + c];
    acc2 = fmaxf(acc2, 0.f);
    int node = bn + nn;
    if (node < n) h0[(size_t)node * 32 + c] = (_Float16)acc2;
}

// ---------------- prep: wt | hist+scatter | enc fused by blockIdx range ----------------
__global__ __launch_bounds__(256)
void prep_kernel(const float* __restrict__ x,
                 const float* __restrict__ ew1, const float* __restrict__ eb1,
                 const float* __restrict__ ew2, const float* __restrict__ eb2,
                 _Float16* __restrict__ h0,
                 const float* __restrict__ q1, const float* __restrict__ k1,
                 const float* __restrict__ v1, _Float16* __restrict__ WT1,
                 const float* __restrict__ q2, const float* __restrict__ k2,
                 const float* __restrict__ v2, _Float16* __restrict__ WT2,
                 const int* __restrict__ srcv, const int* __restrict__ dstv,
                 int* __restrict__ deg, int* __restrict__ colb,
                 int n, int e, int wtb, int histb) {
    __shared__ float smem[3904];
    int b = blockIdx.x, t = threadIdx.x;
    if (b < wtb) {
        // WT[z*128+c][k] = Wz[k][c] (fp16), both convs back to back
        int tid = b * 256 + t;
        const int n1 = 3 * 128 * 32;
        if (tid < n1) {
            int z = tid / (128 * 32);
            int rem = tid % (128 * 32);
            int c = rem / 32, k = rem % 32;
            const float* w = (z == 0) ? q1 : ((z == 1) ? k1 : v1);
            WT1[tid] = (_Float16)w[k * 128 + c];
        } else {
            int i = tid - n1;
            if (i < 3 * 128 * 128) {
                int z = i / (128 * 128);
                int rem = i % (128 * 128);
                int c = rem / 128, k = rem % 128;
                const float* w = (z == 0) ? q2 : ((z == 1) ? k2 : v2);
                WT2[i] = (_Float16)w[k * 128 + c];
            }
        }
    } else if (b < wtb + histb) {
        // fused hist + scatter into padded neighbor rows
        int i = (b - wtb) * 256 + t;
        if (i < e) {
            int d = dstv[i];
            int slot = atomicAdd(&deg[d], 1);
            if (slot < CAP) colb[d * CAP + slot] = srcv[i];
        }
    } else {
        enc_body(x, ew1, eb1, ew2, eb2, h0, n, (b - wtb - histb) * 8, smem);
    }
}

// ---------------- qkv GEMM body via MFMA: Y_z[n x 128] = (X .* mask?) @ Wz + bz -------------
// 256 thr = 4 waves (2x2): wr -> 32 rows, wc -> 64 cols. BM=64, K-tile=32.
// A-frag: lane row=l&15, k=(l>>4)*8+j ; B-frag: lane col=l&15, same k ; C/D: col=l&15, row=(l>>4)*4+reg.
__device__ __forceinline__ void qkv_body(const _Float16* __restrict__ X, const float* __restrict__ mask,
                                         const _Float16* __restrict__ WT,
                                         const float* __restrict__ Bq, const float* __restrict__ Bk,
                                         const float* __restrict__ Bv,
                                         _Float16* __restrict__ Q, _Float16* __restrict__ KV,
                                         int n, int IN, int bx, int z,
                                         _Float16* __restrict__ Xs, _Float16* __restrict__ Ws) {
    int t = threadIdx.x;
    int bm = bx * 64;
    const float* Bz = (z == 0) ? Bq : ((z == 1) ? Bk : Bv);
    _Float16* Y;
    size_t ystride;
    if (z == 0) { Y = Q; ystride = 128; }
    else        { Y = KV + (z == 1 ? 0 : 128); ystride = 256; }

    int lane = t & 63, w = t >> 6;
    int wr = w >> 1, wc = w & 1;
    int fr = lane & 15, k0 = (lane >> 4) * 8;
    f32x4 acc[2][4];
#pragma unroll
    for (int i = 0; i < 2; ++i)
#pragma unroll
        for (int j = 0; j < 4; ++j)
#pragma unroll
            for (int r = 0; r < 4; ++r) acc[i][j][r] = 0.f;

    // staging roles: X -> row t>>2 (0..63), seg (t&3)*8 ; W -> rows t>>2 and 64+(t>>2)
    int srow = t >> 2, sseg = (t & 3) * 8;
    int snode = bm + srow;
    const _Float16* xbase = X + (size_t)snode * IN + sseg;
    const _Float16* wbase = WT + (size_t)(z * 128) * IN + sseg;
    bool xvalid = (snode < n);
    if (xvalid && mask) xvalid = (mask[snode] != 0.f);   // mask is exactly 0/1

    for (int kt = 0; kt < IN; kt += 32) {
        half8 xv = h8zero();
        if (xvalid) xv = *(const half8*)(xbase + kt);
        half8 wv0 = *(const half8*)(wbase + (size_t)srow * IN + kt);
        half8 wv1 = *(const half8*)(wbase + (size_t)(64 + srow) * IN + kt);
        __syncthreads();   // protect LDS reuse from previous iteration
        *(half8*)&Xs[srow * 40 + sseg] = xv;
        *(half8*)&Ws[srow * 40 + sseg] = wv0;
        *(half8*)&Ws[(64 + srow) * 40 + sseg] = wv1;
        __syncthreads();
        half8 a0 = *(const half8*)&Xs[(wr * 32 + fr) * 40 + k0];
        half8 a1 = *(const half8*)&Xs[(wr * 32 + 16 + fr) * 40 + k0];
#pragma unroll
        for (int tc = 0; tc < 4; ++tc) {
            half8 bfr = *(const half8*)&Ws[(wc * 64 + tc * 16 + fr) * 40 + k0];
            acc[0][tc] = __builtin_amdgcn_mfma_f32_16x16x32_f16(a0, bfr, acc[0][tc], 0, 0, 0);
            acc[1][tc] = __builtin_amdgcn_mfma_f32_16x16x32_f16(a1, bfr, acc[1][tc], 0, 0, 0);
        }
    }
#pragma unroll
    for (int tc = 0; tc < 4; ++tc) {
        int colc = wc * 64 + tc * 16 + fr;
        float bias = Bz[colc];
#pragma unroll
        for (int tr = 0; tr < 2; ++tr) {
#pragma unroll
            for (int reg = 0; reg < 4; ++reg) {
                int node = bm + wr * 32 + tr * 16 + (lane >> 4) * 4 + reg;
                if (node < n) Y[(size_t)node * ystride + colc] = (_Float16)(acc[tr][tc][reg] + bias);
            }
        }
    }
}

__global__ __launch_bounds__(256)
void qkv_kernel(const _Float16* __restrict__ X, const float* __restrict__ mask,
                const _Float16* __restrict__ WT,
                const float* __restrict__ Bq, const float* __restrict__ Bk,
                const float* __restrict__ Bv,
                _Float16* __restrict__ Q, _Float16* __restrict__ KV, int n, int IN) {
    __shared__ _Float16 Xs[64 * 40];
    __shared__ _Float16 Ws[128 * 40];
    qkv_body(X, mask, WT, Bq, Bk, Bv, Q, KV, n, IN, blockIdx.x, blockIdx.y, Xs, Ws);
}

// ---------------- attention: one wave per dst node, 4 edge slots, MAX-FREE softmax ----------
// softmax is shift-invariant; logits here are O(1) so exp2 with +/-120 clamp is exact enough.
// lane: es=lane>>4 (4 edge slots); l=lane&15 -> 8 dims at d0=l*8; head = l>>2
__global__ __launch_bounds__(256)
void attn_kernel(const _Float16* __restrict__ q, const _Float16* __restrict__ kv,
                 const int* __restrict__ deg, const int* __restrict__ col,
                 _Float16* __restrict__ out, int n) {
    int w = threadIdx.x >> 6;
    int lane = threadIdx.x & 63;
    int node = blockIdx.x * 4 + w;
    if (node >= n) return;
    int es = lane >> 4;
    int l = lane & 15;
    int d0 = l * 8;
    float qf[8];
    {
        half8 qh = *(const half8*)(q + (size_t)node * 128 + d0);
#pragma unroll
        for (int j = 0; j < 8; ++j) qf[j] = (float)qh[j];
    }
    int start = node * CAP;
    int len = deg[node];
    len = (len > CAP) ? CAP : len;
    float s = 0.f;
    float acc[8];
#pragma unroll
    for (int j = 0; j < 8; ++j) acc[j] = 0.f;
    const float sc = 0.17677669529663689f * 1.4426950408889634f;  // 1/sqrt(32) * log2(e)

    for (int i = es; i < len; i += 4) {
        int srcn = col[start + i];
        const _Float16* row = kv + (size_t)srcn * 256 + d0;
        half8 kf = *(const half8*)row;
        float dot = 0.f;
#pragma unroll
        for (int j = 0; j < 8; ++j) dot += qf[j] * (float)kf[j];
        dot += __shfl_xor(dot, 1);
        dot += __shfl_xor(dot, 2);            // sum over the 4 lanes of this head
        float a = fminf(fmaxf(dot * sc, -120.f), 120.f);
        float p = __builtin_amdgcn_exp2f(a);
        half8 vf = *(const half8*)(row + 128);
        s += p;
#pragma unroll
        for (int j = 0; j < 8; ++j) acc[j] += p * (float)vf[j];
    }
    // merge the four edge slots (pure sums — no max bookkeeping)
#pragma unroll
    for (int half = 16; half <= 32; half <<= 1) {
        s += __shfl_xor(s, half);
#pragma unroll
        for (int j = 0; j < 8; ++j) acc[j] += __shfl_xor(acc[j], half);
    }
    if (es == 0) {
        float inv = 1.f / (s + 1e-16f);
        half8 r;
#pragma unroll
        for (int j = 0; j < 8; ++j) r[j] = (_Float16)fmaxf(acc[j] * inv, 0.f);
        *(half8*)(out + (size_t)node * 128 + d0) = r;
    }
}

// ---------------- output head: concat(x1,x2,x3) @ out_w + out_b ----------------
__global__ void head_kernel(const _Float16* __restrict__ h0, const _Float16* __restrict__ h1,
                            const _Float16* __restrict__ h2, const int* __restrict__ gi,
                            const float* __restrict__ ow, const float* __restrict__ ob,
                            float* __restrict__ out, int bsz) {
    int idx = blockIdx.x * 256 + threadIdx.x;
    if (idx >= bsz * 5) return;
    int b = idx / 5, c = idx % 5;
    int g = gi[b];
    float acc = ob[c];
    const _Float16* r0 = h0 + (size_t)g * 32;
#pragma unroll
    for (int i = 0; i < 32; ++i) acc += (float)r0[i] * ow[i * 5 + c];
    const _Float16* r1 = h1 + (size_t)g * 128;
#pragma unroll
    for (int i = 0; i < 128; ++i) acc += (float)r1[i] * ow[(32 + i) * 5 + c];
    const _Float16* r2 = h2 + (size_t)g * 128;
#pragma unroll
    for (int i = 0; i < 128; ++i) acc += (float)r2[i] * ow[(160 + i) * 5 + c];
    out[idx] = acc;
}

extern "C" void kernel_launch(void* const* d_in, const int* in_sizes, int n_in,
                              void* d_out, int out_size, void* d_ws, size_t ws_size,
                              hipStream_t stream) {
    const float* x    = (const float*)d_in[0];
    const int*   ei   = (const int*)d_in[1];
    const float* dm   = (const float*)d_in[2];
    const int*   gi   = (const int*)d_in[3];
    const float* ew1  = (const float*)d_in[4];
    const float* eb1  = (const float*)d_in[5];
    const float* ew2  = (const float*)d_in[6];
    const float* eb2  = (const float*)d_in[7];
    const float* c1wq = (const float*)d_in[8];
    const float* c1bq = (const float*)d_in[9];
    const float* c1wk = (const float*)d_in[10];
    const float* c1bk = (const float*)d_in[11];
    const float* c1wv = (const float*)d_in[12];
    const float* c1bv = (const float*)d_in[13];
    const float* c2wq = (const float*)d_in[14];
    const float* c2bq = (const float*)d_in[15];
    const float* c2wk = (const float*)d_in[16];
    const float* c2bk = (const float*)d_in[17];
    const float* c2wv = (const float*)d_in[18];
    const float* c2bv = (const float*)d_in[19];
    const float* ow   = (const float*)d_in[20];
    const float* ob   = (const float*)d_in[21];
    float* out = (float*)d_out;

    int N = in_sizes[0] / 64;
    int E = in_sizes[1] / 2;
    int B = in_sizes[3];
    const int* srcv = ei;
    const int* dstv = ei + E;

    // workspace carve-up
    char* ws = (char*)d_ws;
    size_t off = 0;
    auto alloc = [&](size_t bytes) -> void* {
        void* p = ws + off;
        off += (bytes + 255) & ~(size_t)255;
        return p;
    };
    _Float16* h0   = (_Float16*)alloc((size_t)N * 32 * 2);
    _Float16* h1   = (_Float16*)alloc((size_t)N * 128 * 2);
    _Float16* h2   = (_Float16*)alloc((size_t)N * 128 * 2);
    _Float16* Q    = (_Float16*)alloc((size_t)N * 128 * 2);
    _Float16* KV   = (_Float16*)alloc((size_t)N * 256 * 2);
    _Float16* WT1  = (_Float16*)alloc((size_t)3 * 128 * 32 * 2);
    _Float16* WT2  = (_Float16*)alloc((size_t)3 * 128 * 128 * 2);
    int* deg   = (int*)alloc((size_t)N * 4);
    int* colb  = (int*)alloc((size_t)N * CAP * 4);

    hipMemsetAsync(deg, 0, (size_t)N * 4, stream);

    int eb    = (E + 255) / 256;        // 3125
    int encb  = (N + 7) / 8;            // 6250
    int nqx   = (N + 63) / 64;          // 782
    int wtb   = (3 * 128 * 32 + 3 * 128 * 128 + 255) / 256;   // 240

    prep_kernel<<<wtb + eb + encb, 256, 0, stream>>>(
        x, ew1, eb1, ew2, eb2, h0,
        c1wq, c1wk, c1wv, WT1, c2wq, c2wk, c2wv, WT2,
        srcv, dstv, deg, colb, N, E, wtb, eb);

    dim3 gq(nqx, 3);
    // conv1: IN=32
    qkv_kernel<<<gq, 256, 0, stream>>>(h0, nullptr, WT1, c1bq, c1bk, c1bv, Q, KV, N, 32);
    attn_kernel<<<(N + 3) / 4, 256, 0, stream>>>(Q, KV, deg, colb, h1, N);
    // conv2: IN=128, input = h1 * dm_mask (mask fused into staging; x2 gathers unmasked h1)
    qkv_kernel<<<gq, 256, 0, stream>>>(h1, dm, WT2, c2bq, c2bk, c2bv, Q, KV, N, 128);
    attn_kernel<<<(N + 3) / 4, 256, 0, stream>>>(Q, KV, deg, colb, h2, N);

    head_kernel<<<(B * 5 + 255) / 256, 256, 0, stream>>>(h0, h1, h2, gi, ow, ob, out, B);
}